// Round 6
// baseline (170.747 us; speedup 1.0000x reference)
//
#include <hip/hip_runtime.h>
#include <math.h>

namespace {

constexpr int W = 2048, H = 2048, NC = 3, HALF = 1024;
constexpr size_t HWSZ = (size_t)W * H;
constexpr size_t MQ = (size_t)HALF * HALF;
constexpr size_t M2 = 2 * MQ;
constexpr float LAM = 0.05f;

__device__ __forceinline__ int refl(int i, int n) {
    return i < 0 ? -1 - i : (i >= n ? 2 * n - 1 - i : i);
}
__device__ __forceinline__ int iclamp(int v, int lo, int hi) {
    return v < lo ? lo : (v > hi ? hi : v);
}

// cf layout: [0..24]=g, [32..57]=hw(26), [64..91]=cw(28), [96..112]=C0(17), [128..144]=C1(17)
__global__ void prep(const float* __restrict__ k, float* __restrict__ cf) {
    if (threadIdx.x != 0) return;
    float g[25];
#pragma unroll
    for (int p = 0; p < 25; ++p) { g[p] = sqrtf(k[p * 25 + p]); cf[p] = g[p]; }
    float hw[26];
    hw[0] = 0.5f * g[0];
#pragma unroll
    for (int t = 1; t < 25; ++t) hw[t] = 0.5f * (g[t] + g[t - 1]);
    hw[25] = 0.5f * g[24];
#pragma unroll
    for (int t = 0; t < 26; ++t) cf[32 + t] = hw[t];
#pragma unroll
    for (int d = 0; d < 28; ++d) {
        float s = 0.f;
        if (d < 25) s = fmaf(-0.0625f, g[d], s);
        if (d >= 1 && d <= 25) s = fmaf(0.5625f, g[d - 1], s);
        if (d >= 2 && d <= 26) s = fmaf(0.5625f, g[d - 2], s);
        if (d >= 3) s = fmaf(-0.0625f, g[d - 3], s);
        cf[64 + d] = s;
    }
    const float WE4[4] = {-0.0234375f, 0.2265625f, 0.8671875f, -0.0703125f};
    float C0[17], C1[17];
#pragma unroll
    for (int m = 0; m < 17; ++m) { C0[m] = 0.f; C1[m] = 0.f; }
#pragma unroll
    for (int p = 0; p < 2; ++p) {
#pragma unroll
        for (int t = 0; t < 26; ++t) {
            int r = p - 12 + t;
            int fl = (r + 64) / 2 - 32;
            int e = (r + 64) & 1;
#pragma unroll
            for (int b = 0; b < 4; ++b) {
                int m = fl + e + b - 2 + 8;
                float wub = e ? WE4[3 - b] : WE4[b];
                float add = hw[t] * wub;
                if (p == 0) C0[m] += add;
                else C1[m] += add;
            }
        }
    }
#pragma unroll
    for (int m = 0; m < 17; ++m) { cf[96 + m] = C0[m]; cf[128 + m] = C1[m]; }
}

// ---- front: x -> d1 (composite conv+down both axes) AND x -> hx (AA down) ----
__global__ __launch_bounds__(256) void front(const float* __restrict__ x,
                                             float* __restrict__ d1,
                                             float* __restrict__ hx,
                                             const float* __restrict__ cf) {
    __shared__ float xs[90][100];  // stride 100: 16B-aligned rows, 2-way-free banking
    __shared__ float th[90][33];
    int b = blockIdx.x;
    int tx = b & 31, ty = (b >> 5) & 31, c = b >> 10;
    int tid = threadIdx.x;
    const int r0 = 64 * ty - 13;
    const int c0 = 64 * tx - 16;   // 16B aligned loads
    const float* xb = x + (size_t)c * HWSZ;
    // load 90 rows x 24 float4 (96 cols), wrap addressing: xs[r][cc] = x[(r0+r)&2047][(c0+cc)&2047]
    {
        int lane8 = tid & 7;
        int rsub = tid >> 3;
#pragma unroll
        for (int rp = 0; rp < 3; ++rp) {
            int r = rp * 32 + rsub;
            if (r < 90) {
                const float* xr = xb + (size_t)((r0 + r) & 2047) * W;
#pragma unroll
                for (int g4 = 0; g4 < 3; ++g4) {
                    int cc = g4 * 8 + lane8;
                    float4 v = *(const float4*)(xr + ((c0 + 4 * cc) & 2047));
                    *(float4*)&xs[r][4 * cc] = v;
                }
            }
        }
    }
    float g[25], cw[28];
#pragma unroll
    for (int p = 0; p < 25; ++p) g[p] = cf[p];
#pragma unroll
    for (int d = 0; d < 28; ++d) cw[d] = cf[64 + d];
    const bool BROW = (ty == 0 || ty == 31);
    const bool BCOL = (tx == 0 || tx == 31);
    __syncthreads();

    // ---- branch B: AA down. h pass -> th[70][32]
    const float WA[8] = {-0.01171875f, -0.03515625f, 0.11328125f, 0.43359375f,
                         0.43359375f,  0.11328125f,  -0.03515625f, -0.01171875f};
    const int ob_r0 = 64 * ty - 3, ob_c0 = 64 * tx - 3;
    for (int idx = tid; idx < 560; idx += 256) {
        int rr = idx >> 3, q = idx & 7;
        int lr = BROW ? (refl(ob_r0 + rr, H) - r0) : (rr + 10);
        const float* xr = &xs[lr][0];
        float a0 = 0.f, a1 = 0.f, a2 = 0.f, a3 = 0.f;
        if (!BCOL) {
            float xw[16];
#pragma unroll
            for (int v4 = 0; v4 < 4; ++v4)
                *(float4*)&xw[4 * v4] = *(const float4*)(xr + 8 * q + 12 + 4 * v4);
#pragma unroll
            for (int u = 0; u < 8; ++u) {
                a0 = fmaf(WA[u], xw[u + 1], a0);
                a1 = fmaf(WA[u], xw[u + 3], a1);
                a2 = fmaf(WA[u], xw[u + 5], a2);
                a3 = fmaf(WA[u], xw[u + 7], a3);
            }
        } else {
#pragma unroll
            for (int u = 0; u < 14; ++u) {
                float v = xr[refl(ob_c0 + 8 * q + u, W) - c0];
                if (u < 8) a0 = fmaf(WA[u], v, a0);
                if (u >= 2 && u < 10) a1 = fmaf(WA[u - 2], v, a1);
                if (u >= 4 && u < 12) a2 = fmaf(WA[u - 4], v, a2);
                if (u >= 6) a3 = fmaf(WA[u - 6], v, a3);
            }
        }
        th[rr][4 * q + 0] = a0;
        th[rr][4 * q + 1] = a1;
        th[rr][4 * q + 2] = a2;
        th[rr][4 * q + 3] = a3;
    }
    __syncthreads();
    // AA v pass -> hx
    {
        int oc = tid & 31, og = tid >> 5;
        float a0 = 0.f, a1 = 0.f, a2 = 0.f, a3 = 0.f;
#pragma unroll
        for (int u = 0; u < 14; ++u) {
            float v = th[8 * og + u][oc];
            if (u < 8) a0 = fmaf(WA[u], v, a0);
            if (u >= 2 && u < 10) a1 = fmaf(WA[u - 2], v, a1);
            if (u >= 4 && u < 12) a2 = fmaf(WA[u - 4], v, a2);
            if (u >= 6) a3 = fmaf(WA[u - 6], v, a3);
        }
        float* hp = hx + (size_t)c * MQ + (size_t)(32 * ty + 4 * og) * HALF + 32 * tx + oc;
        hp[0] = a0; hp[HALF] = a1; hp[2 * HALF] = a2; hp[3 * HALF] = a3;
    }
    __syncthreads();

    // ---- branch A phase 1: horizontal composite -> th[90][32]
    for (int idx = tid; idx < 720; idx += 256) {
        int r = idx >> 3, q = idx & 7;
        float xw[40];
#pragma unroll
        for (int v4 = 0; v4 < 10; ++v4)
            *(float4*)&xw[4 * v4] = *(const float4*)(&xs[r][8 * q] + 4 * v4);
        float a0 = 0.f, a1 = 0.f, a2 = 0.f, a3 = 0.f;
#pragma unroll
        for (int u = 0; u < 28; ++u) {
            float w = cw[u];
            a0 = fmaf(w, xw[u + 3], a0);
            a1 = fmaf(w, xw[u + 5], a1);
            a2 = fmaf(w, xw[u + 7], a2);
            a3 = fmaf(w, xw[u + 9], a3);
        }
        th[r][4 * q + 0] = a0;
        th[r][4 * q + 1] = a1;
        th[r][4 * q + 2] = a2;
        th[r][4 * q + 3] = a3;
    }
    __syncthreads();
    // exact border columns (wrap taps live in tile: tx==0 at col p+4.., tx==31 at p+65..)
    if (tx == 0) {
        for (int r = tid; r < 90; r += 256) {
            float b0 = 0.f, b1 = 0.f, b2 = 0.f;
#pragma unroll
            for (int p = 0; p < 25; ++p) {
                b0 = fmaf(g[p], xs[r][p + 4], b0);
                b1 = fmaf(g[p], xs[r][p + 5], b1);
                b2 = fmaf(g[p], xs[r][p + 6], b2);
            }
            th[r][0] = 0.5f * b0 + 0.5625f * b1 - 0.0625f * b2;
        }
    }
    if (tx == 31) {
        for (int r = tid; r < 90; r += 256) {
            float b0 = 0.f, b1 = 0.f, b2 = 0.f;
#pragma unroll
            for (int p = 0; p < 25; ++p) {
                b0 = fmaf(g[p], xs[r][p + 65], b0);
                b1 = fmaf(g[p], xs[r][p + 66], b1);
                b2 = fmaf(g[p], xs[r][p + 67], b2);
            }
            th[r][31] = -0.0625f * b0 + 0.5625f * b1 + 0.5f * b2;
        }
    }
    __syncthreads();

    // ---- branch A phase 2: vertical composite -> d1
    {
        int oc = tid & 31, og = tid >> 5;
        float a0 = 0.f, a1 = 0.f, a2 = 0.f, a3 = 0.f;
#pragma unroll
        for (int u = 0; u < 34; ++u) {
            float v = th[8 * og + u][oc];
            if (u < 28) a0 = fmaf(cw[u], v, a0);
            if (u >= 2 && u < 30) a1 = fmaf(cw[u - 2], v, a1);
            if (u >= 4 && u < 32) a2 = fmaf(cw[u - 4], v, a2);
            if (u >= 6) a3 = fmaf(cw[u - 6], v, a3);
        }
        float av[4] = {a0, a1, a2, a3};
        if (ty == 0 && og == 0) {
            float b0 = 0.f, b1 = 0.f, b2 = 0.f;
#pragma unroll
            for (int p = 0; p < 25; ++p) {
                b0 = fmaf(g[p], th[1 + p][oc], b0);
                b1 = fmaf(g[p], th[2 + p][oc], b1);
                b2 = fmaf(g[p], th[3 + p][oc], b2);
            }
            av[0] = 0.5f * b0 + 0.5625f * b1 - 0.0625f * b2;
        }
        if (ty == 31 && og == 7) {
            float b0 = 0.f, b1 = 0.f, b2 = 0.f;
#pragma unroll
            for (int p = 0; p < 25; ++p) {
                b0 = fmaf(g[p], th[62 + p][oc], b0);
                b1 = fmaf(g[p], th[63 + p][oc], b1);
                b2 = fmaf(g[p], th[64 + p][oc], b2);
            }
            av[3] = -0.0625f * b0 + 0.5625f * b1 + 0.5f * b2;
        }
        float* dp = d1 + (size_t)c * MQ + (size_t)(32 * ty + 4 * og) * HALF + 32 * tx + oc;
#pragma unroll
        for (int k = 0; k < 4; ++k) dp[(size_t)k * HALF] = av[k];
    }
}

// ---- aK2: narrow-col composite (interior rows, q-cols [0,32)u[992,1024)) + exact border rows ----
__global__ __launch_bounds__(256) void aK2(const float* __restrict__ d1,
                                           float* __restrict__ m1,
                                           const float* __restrict__ cf) {
    __shared__ float ds2[24][68];
    int b = blockIdx.x;
    int tid = threadIdx.x;
    if (b < 126 * NC) {
        int c = b / 126, ib = b - 126 * c;
        int i0 = 16 + 16 * ib;            // rows [16,2032)
        int q0m = (i0 >> 1) - 8;          // in [0,1000]
        int cc = tid & 63;
        int qcol = cc < 32 ? cc : 960 + cc;
        const float* d1c = d1 + (size_t)c * MQ;
        for (int r = tid >> 6; r < 24; r += 4)
            ds2[r][cc] = d1c[(size_t)(q0m + r) * HALF + qcol];
        __syncthreads();
        float C0[17], C1[17];
#pragma unroll
        for (int m = 0; m < 17; ++m) { C0[m] = cf[96 + m]; C1[m] = cf[128 + m]; }
        float* mc = m1 + (size_t)c * M2;
        int rbase = (tid >> 6) * 4;
#pragma unroll
        for (int k = 0; k < 4; ++k) {
            int rr = rbase + k;
            float a = 0.f;
#pragma unroll
            for (int m = 0; m < 17; ++m) {
                float wgt = (rr & 1) ? C1[m] : C0[m];
                a = fmaf(wgt, ds2[(rr >> 1) + m][cc], a);
            }
            mc[(size_t)(i0 + rr) * HALF + qcol] = a;
        }
    } else {
        int bid = b - 126 * NC;
        int ri = bid & 31, c = bid >> 5;
        int i = ri < 16 ? ri : 2016 + ri;
        float g[25], hw[26];
#pragma unroll
        for (int p = 0; p < 25; ++p) g[p] = cf[p];
#pragma unroll
        for (int t = 0; t < 26; ++t) hw[t] = cf[32 + t];
        const float WE4[4] = {-0.0234375f, 0.2265625f, 0.8671875f, -0.0703125f};
        bool cl = (i == 2047);
        const float* db = d1 + (size_t)c * MQ + 4 * tid;
        float4 a = make_float4(0.f, 0.f, 0.f, 0.f);
#pragma unroll
        for (int t = 0; t < 26; ++t) {
            float wgt = cl ? (t < 25 ? g[t] : 0.f) : hw[t];
            int ip = (i - 12 + t) & 2047;
            int e = ip & 1, qq = (ip >> 1) + e - 2;
            float4 uv = make_float4(0.f, 0.f, 0.f, 0.f);
#pragma unroll
            for (int bq = 0; bq < 4; ++bq) {
                float wu = e ? WE4[3 - bq] : WE4[bq];
                int rr = refl(qq + bq, HALF);
                float4 v = *(const float4*)(db + (size_t)rr * HALF);
                uv.x = fmaf(wu, v.x, uv.x);
                uv.y = fmaf(wu, v.y, uv.y);
                uv.z = fmaf(wu, v.z, uv.z);
                uv.w = fmaf(wu, v.w, uv.w);
            }
            a.x = fmaf(wgt, uv.x, a.x);
            a.y = fmaf(wgt, uv.y, a.y);
            a.z = fmaf(wgt, uv.z, a.z);
            a.w = fmaf(wgt, uv.w, a.w);
        }
        *(float4*)(m1 + (size_t)c * M2 + (size_t)i * HALF + 4 * tid) = a;
    }
}

// ---- bK-main body (4 full-width rows from exact m1): used for border rows ----
__device__ __forceinline__ void bk_rowquad(int i0, int c,
                                           const float* __restrict__ m1,
                                           const float* __restrict__ hx,
                                           float* __restrict__ out,
                                           const float* __restrict__ cf,
                                           float* smem, int tid) {
    float (*mr)[1040] = (float (*)[1040])smem;
    float (*hv)[1040] = (float (*)[1040])(smem + 4160);
    const float WE4[4] = {-0.0234375f, 0.2265625f, 0.8671875f, -0.0703125f};
    float C0[17], C1[17];
#pragma unroll
    for (int m = 0; m < 17; ++m) { C0[m] = cf[96 + m]; C1[m] = cf[128 + m]; }
    const float* mb = m1 + (size_t)c * M2 + (size_t)i0 * HALF;
#pragma unroll
    for (int r = 0; r < 4; ++r) {
        float4 v = *(const float4*)(mb + (size_t)r * HALF + 4 * tid);
        *(float4*)&mr[r][8 + 4 * tid] = v;
    }
    const float* hb = hx + (size_t)c * MQ;
    int q2 = i0 >> 1;
#pragma unroll
    for (int k = 0; k < 4; ++k) {
        float4 a = make_float4(0.f, 0.f, 0.f, 0.f);
#pragma unroll
        for (int aq = 0; aq < 4; ++aq) {
            float wu = (k & 1) ? WE4[3 - aq] : WE4[aq];
            int row = refl(q2 - 2 + (k >> 1) + (k & 1) + aq, HALF);
            float4 v = *(const float4*)(hb + (size_t)row * HALF + 4 * tid);
            a.x = fmaf(wu, v.x, a.x);
            a.y = fmaf(wu, v.y, a.y);
            a.z = fmaf(wu, v.z, a.z);
            a.w = fmaf(wu, v.w, a.w);
        }
        *(float4*)&hv[k][4 + 4 * tid] = a;
        if (tid == 0) { hv[k][3] = a.x; hv[k][2] = a.y; }
        if (tid == 255) { hv[k][4 + 1024] = a.w; hv[k][4 + 1025] = a.z; }
    }
    __syncthreads();
    bool dostore = (tid >= 2 && tid <= 253);
    float* ob = out + (size_t)c * HWSZ + (size_t)i0 * W + 8 * tid;
#pragma unroll
    for (int r = 0; r < 4; ++r) {
        float w[20];
#pragma unroll
        for (int q5 = 0; q5 < 5; ++q5)
            *(float4*)&w[4 * q5] = *(const float4*)&mr[r][4 * tid + 4 * q5];
        float wv[12];
#pragma unroll
        for (int q3 = 0; q3 < 3; ++q3)
            *(float4*)&wv[4 * q3] = *(const float4*)&hv[r][4 * tid + 4 * q3];
        float res[8];
#pragma unroll
        for (int s = 0; s < 8; ++s) {
            int h = s >> 1;
            float a = 0.f;
#pragma unroll
            for (int m = 0; m < 17; ++m)
                a = fmaf((s & 1) ? C1[m] : C0[m], w[h + m], a);
            float uh = 0.f;
#pragma unroll
            for (int bq = 0; bq < 4; ++bq)
                uh = fmaf((s & 1) ? WE4[3 - bq] : WE4[bq], wv[h + (s & 1) + 2 + bq], uh);
            res[s] = fmaf(LAM, uh, a);
        }
        if (dostore) {
            *(float4*)(ob + (size_t)r * W) = make_float4(res[0], res[1], res[2], res[3]);
            *(float4*)(ob + (size_t)r * W + 4) = make_float4(res[4], res[5], res[6], res[7]);
        }
    }
}

// ---- bK2: fused interior (d1,hx -> out, no m1) + border rows + border cols ----
// grid: [0,1536): backF 32x256 tiles; [1536,1560): border-row quads; [1560,2328): border cols
__global__ __launch_bounds__(256) void bK2(const float* __restrict__ d1,
                                           const float* __restrict__ m1,
                                           const float* __restrict__ hx,
                                           float* __restrict__ out,
                                           const float* __restrict__ cf) {
    __shared__ float smem[12192];  // backF: ds[32][148] | ms[32][148] | hs[20][136]
    int b = blockIdx.x;
    int tid = threadIdx.x;
    const float WE4[4] = {-0.0234375f, 0.2265625f, 0.8671875f, -0.0703125f};
    if (b < 512 * NC) {
        // ---------------- backF ----------------
        int c = b >> 9;
        int r2 = b & 511;
        int cb = r2 >> 6, rb = r2 & 63;
        int i0 = 32 * rb, j0 = 256 * cb;
        int q0 = 16 * rb, h0 = 128 * cb;
        float* dsp = smem;            // 32 x 148
        float* msp = smem + 4736;     // 32 x 148
        float* hsp = smem + 9472;     // 20 x 136
        float* hvp = smem;            // overlays dsp after ms is built: 32 x 136
        const float* d1c = d1 + (size_t)c * MQ;
        const float* hxc = hx + (size_t)c * MQ;
        // stage ds: rows q0-8..q0+23, cols h0-8..h0+135 (clamped; clamped cells feed masked outputs only)
        for (int idx = tid; idx < 1152; idx += 256) {   // 32 rows x 36 float4
            int r = idx / 36, s = idx - 36 * r;
            int grow = iclamp(q0 - 8 + r, 0, 1023);
            int gcol = iclamp(h0 - 8 + 4 * s, 0, 1020);
            *(float4*)(dsp + r * 148 + 4 * s) = *(const float4*)(d1c + (size_t)grow * HALF + gcol);
        }
        // stage hs: rows q0-2..q0+17, cols h0-2..h0+129 (clamped)
        for (int idx = tid; idx < 2640; idx += 256) {   // 20 x 132
            int r = idx / 132, cc = idx - 132 * r;
            int grow = iclamp(q0 - 2 + r, 0, 1023);
            int gcol = iclamp(h0 - 2 + cc, 0, 1023);
            hsp[r * 136 + cc] = hxc[(size_t)grow * HALF + gcol];
        }
        float C0[17], C1[17];
#pragma unroll
        for (int m = 0; m < 17; ++m) { C0[m] = cf[96 + m]; C1[m] = cf[128 + m]; }
        __syncthreads();
        // P2a: m-tile = vertical 17-tap composite
        for (int idx = tid; idx < 4608; idx += 256) {   // 32 x 144
            int r = idx / 144, cc = idx - 144 * r;
            const float* base = dsp + (r >> 1) * 148 + cc;
            float a = 0.f;
#pragma unroll
            for (int m = 0; m < 17; ++m) {
                float wgt = (r & 1) ? C1[m] : C0[m];
                a = fmaf(wgt, base[m * 148], a);
            }
            msp[r * 148 + cc] = a;
        }
        __syncthreads();
        // P2b: hv-tile = vertical bicubic up of hx (overlays ds)
        for (int idx = tid; idx < 4224; idx += 256) {   // 32 x 132
            int r = idx / 132, cc = idx - 132 * r;
            const float* hb2 = hsp + ((r >> 1) + (r & 1)) * 136 + cc;
            float a = 0.f;
#pragma unroll
            for (int aq = 0; aq < 4; ++aq) {
                float wgt = (r & 1) ? WE4[3 - aq] : WE4[aq];
                a = fmaf(wgt, hb2[aq * 136], a);
            }
            hvp[r * 136 + cc] = a;
        }
        __syncthreads();
        // P3: horizontal 17-tap composite + LAM * horizontal up
        int jg = tid & 31, rg = tid >> 5;
        int j = j0 + 8 * jg;
        bool pcol = (j >= 16) && (j <= 2024);
        float* outc = out + (size_t)c * HWSZ;
#pragma unroll
        for (int k = 0; k < 4; ++k) {
            int r = rg + 8 * k;
            int i = i0 + r;
            float w20[20];
#pragma unroll
            for (int q5 = 0; q5 < 5; ++q5)
                *(float4*)&w20[4 * q5] = *(const float4*)(msp + r * 148 + 4 * jg + 4 * q5);
            float wv8[8];
#pragma unroll
            for (int q2v = 0; q2v < 2; ++q2v)
                *(float4*)&wv8[4 * q2v] = *(const float4*)(hvp + r * 136 + 4 * jg + 4 * q2v);
            float res[8];
#pragma unroll
            for (int s = 0; s < 8; ++s) {
                int hh = s >> 1;
                float a = 0.f;
#pragma unroll
                for (int m = 0; m < 17; ++m)
                    a = fmaf((s & 1) ? C1[m] : C0[m], w20[hh + m], a);
                float uh = 0.f;
#pragma unroll
                for (int bq = 0; bq < 4; ++bq)
                    uh = fmaf((s & 1) ? WE4[3 - bq] : WE4[bq], wv8[hh + (s & 1) + bq], uh);
                res[s] = fmaf(LAM, uh, a);
            }
            if (pcol && i >= 16 && i < 2032) {
                float* ob = outc + (size_t)i * W + j;
                *(float4*)ob = make_float4(res[0], res[1], res[2], res[3]);
                *(float4*)(ob + 4) = make_float4(res[4], res[5], res[6], res[7]);
            }
        }
    } else if (b < 512 * NC + 8 * NC) {
        // ---------------- border rows x interior cols ----------------
        int t = b - 512 * NC;
        int c = t >> 3, k = t & 7;
        int i0 = (k < 4) ? 4 * k : 2016 + 4 * k;   // {0,4,8,12, 2032,2036,2040,2044}
        bk_rowquad(i0, c, m1, hx, out, cf, smem, tid);
    } else {
        // ---------------- border cols, all rows (exact) ----------------
        int bid = b - (512 * NC + 8 * NC);
        int rg = bid & 255, c = bid >> 8;
        int i = 8 * rg + (tid >> 5);
        int cc = tid & 31;
        int j = cc < 16 ? cc : 2016 + cc;
        float g[25], hw[26];
#pragma unroll
        for (int p = 0; p < 25; ++p) g[p] = cf[p];
#pragma unroll
        for (int t2 = 0; t2 < 26; ++t2) hw[t2] = cf[32 + t2];
        const float* mrow = m1 + (size_t)c * M2 + (size_t)i * HALF;
        bool cl = (j == 2047);
        float val = 0.f;
#pragma unroll
        for (int t2 = 0; t2 < 26; ++t2) {
            float wgt = cl ? (t2 < 25 ? g[t2] : 0.f) : hw[t2];
            int jp = (j - 12 + t2) & 2047;
            int e = jp & 1;
            int qq = (jp >> 1) + e - 2;
            float uh = 0.f;
#pragma unroll
            for (int bq = 0; bq < 4; ++bq)
                uh = fmaf(e ? WE4[3 - bq] : WE4[bq], mrow[refl(qq + bq, HALF)], uh);
            val = fmaf(wgt, uh, val);
        }
        const float* hb = hx + (size_t)c * MQ;
        int qi = (i >> 1) + (i & 1) - 2;
        int qj = (j >> 1) + (j & 1) - 2;
        float hval = 0.f;
#pragma unroll
        for (int aq = 0; aq < 4; ++aq) {
            const float* hr = hb + (size_t)refl(qi + aq, HALF) * HALF;
            float rowa = (i & 1) ? WE4[3 - aq] : WE4[aq];
            float s = 0.f;
#pragma unroll
            for (int bq = 0; bq < 4; ++bq)
                s = fmaf((j & 1) ? WE4[3 - bq] : WE4[bq], hr[refl(qj + bq, HALF)], s);
            hval = fmaf(rowa, s, hval);
        }
        out[(size_t)c * HWSZ + (size_t)i * W + j] = fmaf(LAM, hval, val);
    }
}

} // namespace

extern "C" void kernel_launch(void* const* d_in, const int* in_sizes, int n_in,
                              void* d_out, int out_size, void* d_ws, size_t ws_size,
                              hipStream_t stream) {
    (void)in_sizes; (void)n_in; (void)out_size; (void)ws_size;
    const float* x = (const float*)d_in[0];
    const float* k = (const float*)d_in[1];
    float* ws = (float*)d_ws;
    float* out = (float*)d_out;

    float* hxp = ws;            // 3*MQ
    float* d1 = hxp + 3 * MQ;   // 3*MQ
    float* m1 = d1 + 3 * MQ;    // 3*M2 (only narrow cols + border rows written/read)
    float* cf = m1 + 3 * M2;    // 160 floats

    hipLaunchKernelGGL(prep, dim3(1), dim3(32), 0, stream, k, cf);
    hipLaunchKernelGGL(front, dim3(32 * 32 * NC), dim3(256), 0, stream, x, d1, hxp, cf);
    hipLaunchKernelGGL(aK2, dim3(126 * NC + 32 * NC), dim3(256), 0, stream, d1, m1, cf);
    hipLaunchKernelGGL(bK2, dim3(512 * NC + 8 * NC + 256 * NC), dim3(256), 0, stream,
                       d1, m1, hxp, out, cf);
}